// Round 3
// baseline (254.353 us; speedup 1.0000x reference)
//
#include <hip/hip_runtime.h>

#define B_SZ 8192
#define F_BASE 256

// ---------------- masks (exact 1.5-entmax via bisection) + fused params ----------------
struct MaskArgs {
  const float* fm[6];
  const float* cp[6];
  const float* lr[6];
  float* out_masks;  // d_out base
  float4* prm;       // fused params {c10, ml0, ml1, 0}
  float* cstf;       // flat per-output 0.5*sum(ml): level d at 2*cstOff[d]
};

__device__ __forceinline__ float wave_max(float v) {
#pragma unroll
  for (int o = 32; o > 0; o >>= 1) v = fmaxf(v, __shfl_xor(v, o));
  return v;
}
__device__ __forceinline__ float wave_sum(float v) {
#pragma unroll
  for (int o = 32; o > 0; o >>= 1) v += __shfl_xor(v, o);
  return v;
}

__global__ __launch_bounds__(64) void ndt_masks(MaskArgs a) {
  const int maskOff[6] = {524288, 524544, 525060, 526100, 528212, 532564};
  const int prmOff[6]  = {0, 256, 772, 1812, 3924, 8276};
  const int cstOff[6]  = {0, 1, 3, 7, 15, 31};
  int bid = blockIdx.x, lane = threadIdx.x;
  int d = 0, s = bid, n = 1;
  while (s >= n) { s -= n; n <<= 1; ++d; }   // level d, stump s, n = 2^d
  int Fd = F_BASE + ((d > 0) ? n : 0);

  const float* fm = a.fm[d] + (size_t)s * Fd;
  float y[5];
#pragma unroll
  for (int j = 0; j < 5; ++j) {
    int f = lane + 64 * j;
    y[j] = (f < Fd) ? fm[f] * 0.5f : -3.0e38f;
  }
  float m = fmaxf(fmaxf(fmaxf(y[0], y[1]), fmaxf(y[2], y[3])), y[4]);
  m = wave_max(m);
#pragma unroll
  for (int j = 0; j < 5; ++j) y[j] -= m;

  // solve sum clip(y - tau, 0)^2 = 1 ; tau in [-1, 0], strictly decreasing in tau
  float lo = -1.f, hi = 0.f;
  for (int it = 0; it < 40; ++it) {
    float tau = 0.5f * (lo + hi);
    float ss = 0.f;
#pragma unroll
    for (int j = 0; j < 5; ++j) {
      float v = fmaxf(y[j] - tau, 0.f);
      ss = __builtin_fmaf(v, v, ss);
    }
    ss = wave_sum(ss);
    if (ss >= 1.f) lo = tau; else hi = tau;
  }
  float tau = 0.5f * (lo + hi);

  float* mo = a.out_masks + maskOff[d] + (size_t)s * Fd;
  const float* cp = a.cp[d] + (size_t)s * Fd * 2;
  const float* lr = a.lr[d] + (size_t)s * Fd * 2;
  float4* pr = a.prm + prmOff[d] + (size_t)s * Fd;
  float sum0 = 0.f, sum1 = 0.f;
#pragma unroll
  for (int j = 0; j < 5; ++j) {
    int f = lane + 64 * j;
    if (f < Fd) {
      float v = fmaxf(y[j] - tau, 0.f);
      float mk = v * v;
      mo[f] = mk;
      float c0 = cp[2 * f], c1 = cp[2 * f + 1];
      float ml0 = lr[2 * f] * mk, ml1 = lr[2 * f + 1] * mk;
      sum0 += ml0;
      sum1 += ml1;
      pr[f] = make_float4(c1 - c0, ml0, ml1, 0.f);
    }
  }
  sum0 = wave_sum(sum0);
  sum1 = wave_sum(sum1);
  if (lane == 0) {
    a.cstf[2 * (cstOff[d] + s)] = 0.5f * sum0;
    a.cstf[2 * (cstOff[d] + s) + 1] = 0.5f * sum1;
  }
}

// 2-elem entmax15 closed form: t = c10 - x; tc = clamp(t,-2,2);
// e = tc*sqrt(0.125 - tc^2/64); p0 = 0.5+e, p1 = 0.5-e.
__device__ __forceinline__ float entpair(float c10, float xv) {
  float t = c10 - xv;
  float tc = __builtin_amdgcn_fmed3f(t, -2.f, 2.f);
  float u = __builtin_fmaf(tc * tc, -0.015625f, 0.125f);
  return tc * __builtin_amdgcn_sqrtf(u);
}

// Butterfly reduce-scatter across the 64-lane wave: input v[j] = this lane's partial
// for output j; output: v[0] = full sum for output (lane & (O-1)).
template <int O>
__device__ __forceinline__ void reduce_scatter(float (&v)[O], int lane) {
#pragma unroll
  for (int d = 32; d >= O; d >>= 1) {
#pragma unroll
    for (int j = 0; j < O; ++j) v[j] += __shfl_xor(v[j], d);
  }
#pragma unroll
  for (int d = O / 2; d >= 1; d >>= 1) {
    bool hi = (lane & d) != 0;
#pragma unroll
    for (int j = 0; j < d; ++j) {
      float send = hi ? v[j] : v[j + d];
      float keep = hi ? v[j + d] : v[j];
      v[j] = keep + __shfl_xor(send, d);
    }
  }
}

// Per-level partial accumulation: lanes span features (4x64 base + EX tail).
template <int NS, int FD>
__device__ __forceinline__ void level_partials(const float4* __restrict__ lds,
                                               const float xv[4], float xe, int lane,
                                               float (&v)[2 * NS]) {
  constexpr int EX = FD - 256;
#pragma unroll
  for (int s = 0; s < NS; ++s) {
    float a0 = 0.f, a1 = 0.f;
#pragma unroll
    for (int j = 0; j < 4; ++j) {
      float4 c = lds[s * FD + lane + 64 * j];
      float e = entpair(c.x, xv[j]);
      a0 = __builtin_fmaf(e, c.y, a0);
      a1 = __builtin_fmaf(-e, c.z, a1);
    }
    if (EX > 0 && lane < EX) {
      float4 c = lds[s * FD + 256 + lane];
      float e = entpair(c.x, xe);
      a0 = __builtin_fmaf(e, c.y, a0);
      a1 = __builtin_fmaf(-e, c.z, a1);
    }
    v[2 * s] = a0;
    v[2 * s + 1] = a1;
  }
}

// ---------------- levels 0-3 fused: wave per row, params in LDS ----------------
__global__ __launch_bounds__(1024) void ndt_fuse03(const float* __restrict__ x,
                                                   const float4* __restrict__ prm,
                                                   const float* __restrict__ cstf,
                                                   float* __restrict__ out3) {
  __shared__ float4 lds[3924];
  int tid = threadIdx.x;
  for (int i = tid; i < 3924; i += 1024) lds[i] = prm[i];
  __syncthreads();
  int w = tid >> 6, lane = tid & 63;
  int b = blockIdx.x * 16 + w;
  float xv[4];
#pragma unroll
  for (int j = 0; j < 4; ++j) xv[j] = x[(size_t)b * 256 + lane + 64 * j];
  float xe = 0.f;
  {  // level 0: 1 stump, FD=256
    float v[2];
    level_partials<1, 256>(lds + 0, xv, xe, lane, v);
    reduce_scatter<2>(v, lane);
    xe = v[0] + cstf[0 + (lane & 1)];
  }
  {  // level 1: 2 stumps, FD=258
    float v[4];
    level_partials<2, 258>(lds + 256, xv, xe, lane, v);
    reduce_scatter<4>(v, lane);
    xe = v[0] + cstf[2 + (lane & 3)];
  }
  {  // level 2: 4 stumps, FD=260
    float v[8];
    level_partials<4, 260>(lds + 772, xv, xe, lane, v);
    reduce_scatter<8>(v, lane);
    xe = v[0] + cstf[6 + (lane & 7)];
  }
  {  // level 3: 8 stumps, FD=264
    float v[16];
    level_partials<8, 264>(lds + 1812, xv, xe, lane, v);
    reduce_scatter<16>(v, lane);
    float res = v[0] + cstf[14 + (lane & 15)];
    if (lane < 16) out3[(size_t)b * 16 + lane] = res;
  }
}

// ---------------- level 4: 16 stumps, FD=272 ----------------
__global__ __launch_bounds__(1024) void ndt_lvl4(const float* __restrict__ x,
                                                 const float* __restrict__ in3,
                                                 const float4* __restrict__ prm,
                                                 const float* __restrict__ cstf,
                                                 float* __restrict__ out4) {
  __shared__ float4 lds[4352];
  int tid = threadIdx.x;
  for (int i = tid; i < 4352; i += 1024) lds[i] = prm[3924 + i];
  __syncthreads();
  int w = tid >> 6, lane = tid & 63;
  int b = blockIdx.x * 16 + w;
  float xv[4];
#pragma unroll
  for (int j = 0; j < 4; ++j) xv[j] = x[(size_t)b * 256 + lane + 64 * j];
  float xe = (lane < 16) ? in3[(size_t)b * 16 + lane] : 0.f;
  float v[32];
  level_partials<16, 272>(lds, xv, xe, lane, v);
  reduce_scatter<32>(v, lane);
  float res = v[0] + cstf[30 + (lane & 31)];
  if (lane < 32) out4[(size_t)b * 32 + lane] = res;
}

// ---------------- level 5: 32 stumps, FD=288, split into 2 halves of 16 ----------------
__global__ __launch_bounds__(1024) void ndt_lvl5(const float* __restrict__ x,
                                                 const float* __restrict__ in4,
                                                 const float4* __restrict__ prm,
                                                 const float* __restrict__ cstf,
                                                 float* __restrict__ out) {
  __shared__ float4 lds[4608];
  int tid = threadIdx.x;
  int half = blockIdx.y;
  const float4* src = prm + 8276 + half * 4608;
  for (int i = tid; i < 4608; i += 1024) lds[i] = src[i];
  __syncthreads();
  int w = tid >> 6, lane = tid & 63;
  int b = blockIdx.x * 16 + w;
  float xv[4];
#pragma unroll
  for (int j = 0; j < 4; ++j) xv[j] = x[(size_t)b * 256 + lane + 64 * j];
  float xe = (lane < 32) ? in4[(size_t)b * 32 + lane] : 0.f;
  float v[32];
  level_partials<16, 288>(lds, xv, xe, lane, v);
  reduce_scatter<32>(v, lane);
  float res = v[0] + cstf[62 + half * 32 + (lane & 31)];
  if (lane < 32) out[(size_t)b * 64 + half * 32 + lane] = res;
}

extern "C" void kernel_launch(void* const* d_in, const int* in_sizes, int n_in,
                              void* d_out, int out_size, void* d_ws, size_t ws_size,
                              hipStream_t stream) {
  const float* x = (const float*)d_in[0];
  float* out = (float*)d_out;
  float* wsf = (float*)d_ws;

  // ws layout (float offsets)
  float* out3 = wsf + 0;       // [8192][16]
  float* out4 = wsf + 131072;  // [8192][32]
  float4* prm = (float4*)(wsf + 2605056);  // 17492 float4
  float* cstf = wsf + 2675024;             // 126 floats

  MaskArgs ma;
  for (int d = 0; d < 6; ++d) {
    ma.fm[d] = (const float*)d_in[1 + 3 * d];
    ma.cp[d] = (const float*)d_in[2 + 3 * d];
    ma.lr[d] = (const float*)d_in[3 + 3 * d];
  }
  ma.out_masks = out;
  ma.prm = prm;
  ma.cstf = cstf;
  hipLaunchKernelGGL(ndt_masks, dim3(63), dim3(64), 0, stream, ma);

  hipLaunchKernelGGL(ndt_fuse03, dim3(B_SZ / 16), dim3(1024), 0, stream,
                     x, prm, cstf, out3);
  hipLaunchKernelGGL(ndt_lvl4, dim3(B_SZ / 16), dim3(1024), 0, stream,
                     x, out3, prm, cstf, out4);
  hipLaunchKernelGGL(ndt_lvl5, dim3(B_SZ / 16, 2), dim3(1024), 0, stream,
                     x, out4, prm, cstf, out);
}

// Round 4
// 111.133 us; speedup vs baseline: 2.2887x; 2.2887x over previous
//
#include <hip/hip_runtime.h>

#define B_SZ 8192

// ---------------- masks (exact 1.5-entmax via bisection) + fused params ----------------
struct MaskArgs {
  const float* fm[6];
  const float* cp[6];
  const float* lr[6];
  float* out_masks;  // d_out base
  float4* prm;       // fused params {c10, ml0, ml1, 0}
  float* cstf;       // flat per-output 0.5*sum(ml): level d at 2*cstOff[d]
};

__device__ __forceinline__ float wave_max(float v) {
#pragma unroll
  for (int o = 32; o > 0; o >>= 1) v = fmaxf(v, __shfl_xor(v, o));
  return v;
}
__device__ __forceinline__ float wave_sum(float v) {
#pragma unroll
  for (int o = 32; o > 0; o >>= 1) v += __shfl_xor(v, o);
  return v;
}

__global__ __launch_bounds__(64) void ndt_masks(MaskArgs a) {
  const int maskOff[6] = {524288, 524544, 525060, 526100, 528212, 532564};
  const int prmOff[6]  = {0, 256, 772, 1812, 3924, 8276};
  const int cstOff[6]  = {0, 1, 3, 7, 15, 31};
  int bid = blockIdx.x, lane = threadIdx.x;
  int d = 0, s = bid, n = 1;
  while (s >= n) { s -= n; n <<= 1; ++d; }   // level d, stump s, n = 2^d
  int Fd = 256 + ((d > 0) ? n : 0);

  const float* fm = a.fm[d] + (size_t)s * Fd;
  float y[5];
#pragma unroll
  for (int j = 0; j < 5; ++j) {
    int f = lane + 64 * j;
    y[j] = (f < Fd) ? fm[f] * 0.5f : -3.0e38f;
  }
  float m = fmaxf(fmaxf(fmaxf(y[0], y[1]), fmaxf(y[2], y[3])), y[4]);
  m = wave_max(m);
#pragma unroll
  for (int j = 0; j < 5; ++j) y[j] -= m;

  // solve sum clip(y - tau, 0)^2 = 1 ; tau in [-1, 0], strictly decreasing in tau
  float lo = -1.f, hi = 0.f;
  for (int it = 0; it < 40; ++it) {
    float tau = 0.5f * (lo + hi);
    float ss = 0.f;
#pragma unroll
    for (int j = 0; j < 5; ++j) {
      float v = fmaxf(y[j] - tau, 0.f);
      ss = __builtin_fmaf(v, v, ss);
    }
    ss = wave_sum(ss);
    if (ss >= 1.f) lo = tau; else hi = tau;
  }
  float tau = 0.5f * (lo + hi);

  float* mo = a.out_masks + maskOff[d] + (size_t)s * Fd;
  const float* cp = a.cp[d] + (size_t)s * Fd * 2;
  const float* lr = a.lr[d] + (size_t)s * Fd * 2;
  float4* pr = a.prm + prmOff[d] + (size_t)s * Fd;
  float sum0 = 0.f, sum1 = 0.f;
#pragma unroll
  for (int j = 0; j < 5; ++j) {
    int f = lane + 64 * j;
    if (f < Fd) {
      float v = fmaxf(y[j] - tau, 0.f);
      float mk = v * v;
      mo[f] = mk;
      float c0 = cp[2 * f], c1 = cp[2 * f + 1];
      float ml0 = lr[2 * f] * mk, ml1 = lr[2 * f + 1] * mk;
      sum0 += ml0;
      sum1 += ml1;
      pr[f] = make_float4(c1 - c0, ml0, ml1, 0.f);
    }
  }
  sum0 = wave_sum(sum0);
  sum1 = wave_sum(sum1);
  if (lane == 0) {
    a.cstf[2 * (cstOff[d] + s)] = 0.5f * sum0;
    a.cstf[2 * (cstOff[d] + s) + 1] = 0.5f * sum1;
  }
}

// 2-elem entmax15 closed form: t = c10 - x; tc = clamp(t,-2,2);
// e = tc*sqrt(0.125 - tc^2/64); p0 = 0.5+e, p1 = 0.5-e.
__device__ __forceinline__ float entpair(float c10, float xv) {
  float t = c10 - xv;
  float tc = __builtin_amdgcn_fmed3f(t, -2.f, 2.f);
  float u = __builtin_fmaf(tc * tc, -0.015625f, 0.125f);
  return tc * __builtin_amdgcn_sqrtf(u);
}

// Butterfly reduce-scatter across 64 lanes: v[j] = partial for output j on entry;
// on exit v[0] = full sum for output (lane & (O-1)). ALL loops fully unrolled.
template <int O>
__device__ __forceinline__ void reduce_scatter(float (&v)[O], int lane) {
#pragma unroll
  for (int d = 32; d >= O; d >>= 1) {
#pragma unroll
    for (int j = 0; j < O; ++j) v[j] += __shfl_xor(v[j], d);
  }
#pragma unroll
  for (int d = O / 2; d >= 1; d >>= 1) {
    bool hi = (lane & d) != 0;
#pragma unroll
    for (int j = 0; j < d; ++j) {
      float send = hi ? v[j] : v[j + d];
      float keep = hi ? v[j + d] : v[j];
      v[j] = keep + __shfl_xor(send, d);
    }
  }
}

// Per-level partials, R rows per lane; lanes span features. Fully unrolled.
template <int NS, int FD, int R>
__device__ __forceinline__ void level_partials(const float4* __restrict__ lds,
                                               const float (&xv)[R][4],
                                               const float (&xe)[R], int lane,
                                               float (&v)[R][2 * NS]) {
  constexpr int EX = FD - 256;
#pragma unroll
  for (int s = 0; s < NS; ++s) {
#pragma unroll
    for (int r = 0; r < R; ++r) {
      v[r][2 * s] = 0.f;
      v[r][2 * s + 1] = 0.f;
    }
#pragma unroll
    for (int j = 0; j < 4; ++j) {
      float4 c = lds[s * FD + lane + 64 * j];
#pragma unroll
      for (int r = 0; r < R; ++r) {
        float e = entpair(c.x, xv[r][j]);
        v[r][2 * s] = __builtin_fmaf(e, c.y, v[r][2 * s]);
        v[r][2 * s + 1] = __builtin_fmaf(-e, c.z, v[r][2 * s + 1]);
      }
    }
    if (EX > 0 && lane < EX) {
      float4 c = lds[s * FD + 256 + lane];
#pragma unroll
      for (int r = 0; r < R; ++r) {
        float e = entpair(c.x, xe[r]);
        v[r][2 * s] = __builtin_fmaf(e, c.y, v[r][2 * s]);
        v[r][2 * s + 1] = __builtin_fmaf(-e, c.z, v[r][2 * s + 1]);
      }
    }
  }
}

// ---------------- levels 0-3 fused: wave per 2 rows, params in LDS ----------------
__global__ __launch_bounds__(1024) void ndt_fuse03(const float* __restrict__ x,
                                                   const float4* __restrict__ prm,
                                                   const float* __restrict__ cstf,
                                                   float* __restrict__ out3) {
  __shared__ float4 lds[3924];
  int tid = threadIdx.x;
  for (int i = tid; i < 3924; i += 1024) lds[i] = prm[i];
  __syncthreads();
  int w = tid >> 6, lane = tid & 63;
  int b = blockIdx.x * 32 + w * 2;
  float xv[2][4];
#pragma unroll
  for (int r = 0; r < 2; ++r)
#pragma unroll
    for (int j = 0; j < 4; ++j) xv[r][j] = x[(size_t)(b + r) * 256 + lane + 64 * j];
  float xe[2] = {0.f, 0.f};
  {  // level 0
    float v[2][2];
    level_partials<1, 256, 2>(lds, xv, xe, lane, v);
#pragma unroll
    for (int r = 0; r < 2; ++r) {
      reduce_scatter<2>(v[r], lane);
      xe[r] = v[r][0] + cstf[lane & 1];
    }
  }
  {  // level 1
    float v[2][4];
    level_partials<2, 258, 2>(lds + 256, xv, xe, lane, v);
#pragma unroll
    for (int r = 0; r < 2; ++r) {
      reduce_scatter<4>(v[r], lane);
      xe[r] = v[r][0] + cstf[2 + (lane & 3)];
    }
  }
  {  // level 2
    float v[2][8];
    level_partials<4, 260, 2>(lds + 772, xv, xe, lane, v);
#pragma unroll
    for (int r = 0; r < 2; ++r) {
      reduce_scatter<8>(v[r], lane);
      xe[r] = v[r][0] + cstf[6 + (lane & 7)];
    }
  }
  {  // level 3
    float v[2][16];
    level_partials<8, 264, 2>(lds + 1812, xv, xe, lane, v);
#pragma unroll
    for (int r = 0; r < 2; ++r) {
      reduce_scatter<16>(v[r], lane);
      float res = v[r][0] + cstf[14 + (lane & 15)];
      if (lane < 16) out3[(size_t)(b + r) * 16 + lane] = res;
    }
  }
}

// ---------------- big levels (4,5): lane <-> row, uniform (scalar) params ----------
// Block: 256 thr = 4 waves sharing a 64-row x-tile in LDS ([f][row], xor-swizzled).
// Wave w handles NSW stumps; each lane accumulates full sums for its row: NO shuffles.
template <int EX, int NSW>
__global__ __launch_bounds__(256) void ndt_big(const float* __restrict__ x,
                                               const float* __restrict__ prev,
                                               const float4* __restrict__ prmL,
                                               const float* __restrict__ cstL,
                                               float* __restrict__ outp,
                                               int outStride) {
  constexpr int FD = 256 + EX;
  __shared__ float xls[256 * 64];
  int tid = threadIdx.x;
  int lane = tid & 63;
  int w = __builtin_amdgcn_readfirstlane(tid >> 6);  // force SGPR -> scalar param loads
  int b0 = blockIdx.x * 64;

  // prev-level outputs of THIS lane's row -> registers (issued before barrier)
  float pv[EX];
  const float4* pvp = (const float4*)(prev + (size_t)(b0 + lane) * EX);
#pragma unroll
  for (int k = 0; k < EX / 4; ++k) {
    float4 t = pvp[k];
    pv[4 * k] = t.x;
    pv[4 * k + 1] = t.y;
    pv[4 * k + 2] = t.z;
    pv[4 * k + 3] = t.w;
  }

  // stage x[b0..b0+63][0..255] -> xls[f][row] with col = row ^ ((f>>2)&31)
#pragma unroll
  for (int k = 0; k < 16; ++k) {
    int row = 4 * k + w;  // wave-uniform
    float4 g = *(const float4*)(x + (size_t)(b0 + row) * 256 + 4 * lane);
    int col = row ^ (lane & 31);
    int base = 4 * lane * 64 + col;
    xls[base] = g.x;
    xls[base + 64] = g.y;
    xls[base + 128] = g.z;
    xls[base + 192] = g.w;
  }
  __syncthreads();

  int s0 = blockIdx.y * (4 * NSW) + w * NSW;
  const float4* pp = prmL + (size_t)s0 * FD;
  float acc[2 * NSW];
#pragma unroll
  for (int i = 0; i < 2 * NSW; ++i) acc[i] = 0.f;

#pragma unroll 4
  for (int f4 = 0; f4 < 64; ++f4) {
    int col = lane ^ (f4 & 31);
    int base = f4 * 256 + col;
#pragma unroll
    for (int kk = 0; kk < 4; ++kk) {
      float xvv = xls[base + kk * 64];
#pragma unroll
      for (int s = 0; s < NSW; ++s) {
        float4 c = pp[s * FD + 4 * f4 + kk];
        float e = entpair(c.x, xvv);
        acc[2 * s] = __builtin_fmaf(e, c.y, acc[2 * s]);
        acc[2 * s + 1] = __builtin_fmaf(-e, c.z, acc[2 * s + 1]);
      }
    }
  }
  // tail: extra features = prev outputs (registers)
#pragma unroll
  for (int o = 0; o < EX; ++o) {
#pragma unroll
    for (int s = 0; s < NSW; ++s) {
      float4 c = pp[s * FD + 256 + o];
      float e = entpair(c.x, pv[o]);
      acc[2 * s] = __builtin_fmaf(e, c.y, acc[2 * s]);
      acc[2 * s + 1] = __builtin_fmaf(-e, c.z, acc[2 * s + 1]);
    }
  }
#pragma unroll
  for (int s = 0; s < NSW; ++s) {
    acc[2 * s] += cstL[2 * (s0 + s)];
    acc[2 * s + 1] += cstL[2 * (s0 + s) + 1];
  }
  float* op = outp + (size_t)(b0 + lane) * outStride + 2 * s0;
  if (NSW == 2) {
    *(float4*)op = make_float4(acc[0], acc[1], acc[2], acc[3]);
  } else {
    *(float2*)op = make_float2(acc[0], acc[1]);
  }
}

extern "C" void kernel_launch(void* const* d_in, const int* in_sizes, int n_in,
                              void* d_out, int out_size, void* d_ws, size_t ws_size,
                              hipStream_t stream) {
  const float* x = (const float*)d_in[0];
  float* out = (float*)d_out;
  float* wsf = (float*)d_ws;

  // ws layout (float offsets)
  float* out3 = wsf + 0;                   // [8192][16]
  float* out4 = wsf + 131072;              // [8192][32]
  float4* prm = (float4*)(wsf + 2605056);  // 17492 float4
  float* cstf = wsf + 2675024;             // 126 floats

  MaskArgs ma;
  for (int d = 0; d < 6; ++d) {
    ma.fm[d] = (const float*)d_in[1 + 3 * d];
    ma.cp[d] = (const float*)d_in[2 + 3 * d];
    ma.lr[d] = (const float*)d_in[3 + 3 * d];
  }
  ma.out_masks = out;
  ma.prm = prm;
  ma.cstf = cstf;
  hipLaunchKernelGGL(ndt_masks, dim3(63), dim3(64), 0, stream, ma);

  hipLaunchKernelGGL(ndt_fuse03, dim3(B_SZ / 32), dim3(1024), 0, stream,
                     x, prm, cstf, out3);

  // level 4: 16 stumps; grid (128 row-blocks, 4 stump-groups), 1 stump/wave
  hipLaunchKernelGGL((ndt_big<16, 1>), dim3(B_SZ / 64, 4), dim3(256), 0, stream,
                     x, out3, prm + 3924, cstf + 30, out4, 32);
  // level 5: 32 stumps; grid (128, 4), 2 stumps/wave
  hipLaunchKernelGGL((ndt_big<32, 2>), dim3(B_SZ / 64, 4), dim3(256), 0, stream,
                     x, out4, prm + 8276, cstf + 62, out, 64);
}